// Round 2
// baseline (19851.120 us; speedup 1.0000x reference)
//
#include <hip/hip_runtime.h>

// ============================================================================
// AttnDecoderRNN round 7: R6 post-mortem = partial-K atomicAdd scheme caused
// 1.3M contended LLC atomics/step (WRITE_SIZE 0.6->1.5GB).  R7: full-K
// weight-sliced GEMMs (single writer per address, ZERO atomics in loop),
// 64-block grid, 3 cheap (64-arrival) barriers/step:
//   P1 (20 blocks/160 waves): [q | gh+bhh | logits+bout] = h @ Wcat^T,
//       h staged once/block into XOR-swizzled LDS (1 batched LLC round trip).
//   P2 (64 blocks, 1/batch): attention, block-local softmax+ctx (R6 style).
//   P3 (32 blocks): gi = Wih.ctx full-K; GRU; h slice persists in LDS f32,
//       broadcast to LLC as bf16 only.
// ============================================================================

typedef short s8v __attribute__((ext_vector_type(8)));
typedef float f4v __attribute__((ext_vector_type(4)));
typedef float f2v __attribute__((ext_vector_type(2)));
typedef unsigned long long u64;

// ws byte offsets
#define OFF_BAR   0u
#define OFF_HBF   4096u        // 64x512 bf16 h broadcast
#define OFF_Q     69632u       // 64x512 f32
#define OFF_GH    200704u      // 64x1536 f32 (includes bhh)
#define OFF_CTX   593920u      // 64x512 bf16 (normalized)
#define OFF_WCAT  659456u      // 2560x512 bf16 : Wa | Whh | Wout
#define OFF_WIH   3280896u     // 1536x512 bf16
#define OFF_KEYS  4853760u     // 64x512x256 bf16 keysT[b][h][s] = exp(2*key)
#define OFF_ENC8  21630976u    // 64x256x512 fp8
#define WS_FULL   30019584u
#define MEMSET_BYTES 69632u    // bar + hbf

// d_out offsets (floats)
#define OUT_LOGITS 0u
#define OUT_HFIN   8388608u
#define OUT_ATTN   8421376u

__device__ __forceinline__ unsigned short f2bf(float f) {
  union { float f; unsigned u; } a; a.f = f;
  unsigned r = a.u + 0x7fffu + ((a.u >> 16) & 1u);
  return (unsigned short)(r >> 16);
}
__device__ __forceinline__ float bf2f(unsigned short h) {
  union { unsigned u; float f; } a; a.u = (unsigned)h << 16; return a.f;
}
__device__ __forceinline__ float cload(const float* p) {
  return __hip_atomic_load(p, __ATOMIC_RELAXED, __HIP_MEMORY_SCOPE_AGENT);
}
__device__ __forceinline__ void cstore(float* p, float v) {
  __hip_atomic_store(p, v, __ATOMIC_RELAXED, __HIP_MEMORY_SCOPE_AGENT);
}
__device__ __forceinline__ void cstoreu(unsigned* p, unsigned v) {
  __hip_atomic_store(p, v, __ATOMIC_RELAXED, __HIP_MEMORY_SCOPE_AGENT);
}
__device__ __forceinline__ u64 cload64(const u64* p) {
  return __hip_atomic_load(p, __ATOMIC_RELAXED, __HIP_MEMORY_SCOPE_AGENT);
}
__device__ __forceinline__ void cstore64(u64* p, u64 v) {
  __hip_atomic_store(p, v, __ATOMIC_RELAXED, __HIP_MEMORY_SCOPE_AGENT);
}
__device__ __forceinline__ float sigm(float x) {
  return __builtin_amdgcn_rcpf(1.f + __expf(-x));
}
__device__ __forceinline__ float tanh2(float x) {
  return 1.f - 2.f * __builtin_amdgcn_rcpf(1.f + __expf(x + x));
}
__device__ __forceinline__ f4v mfma16(s8v a, s8v b, f4v c) {
  return __builtin_amdgcn_mfma_f32_16x16x32_bf16(a, b, c, 0, 0, 0);
}

// two-level barrier for 64 blocks: 8 leaves x 8.  root@bar[0], leaves@bar[16+
// 16l], flags@bar[160+16l], all on separate 64B lines.
__device__ __forceinline__ void gbar(unsigned* bar, unsigned& gen) {
  asm volatile("s_waitcnt vmcnt(0) lgkmcnt(0)" ::: "memory");
  __syncthreads();
  if (threadIdx.x == 0) {
    __atomic_signal_fence(__ATOMIC_SEQ_CST);
    gen++;
    const int leaf = blockIdx.x >> 3;
    unsigned old = __hip_atomic_fetch_add(bar + 16 + leaf * 16, 1u,
                                          __ATOMIC_RELAXED, __HIP_MEMORY_SCOPE_AGENT);
    if (old == gen * 8u - 1u) {
      unsigned ro = __hip_atomic_fetch_add(bar, 1u, __ATOMIC_RELAXED,
                                           __HIP_MEMORY_SCOPE_AGENT);
      if (ro == gen * 8u - 1u) {
#pragma unroll
        for (int l = 0; l < 8; ++l)
          __hip_atomic_store(bar + 160 + l * 16, gen, __ATOMIC_RELAXED,
                             __HIP_MEMORY_SCOPE_AGENT);
      }
    }
    while (__hip_atomic_load(bar + 160 + leaf * 16, __ATOMIC_RELAXED,
                             __HIP_MEMORY_SCOPE_AGENT) < gen)
      __builtin_amdgcn_s_sleep(1);
    __atomic_signal_fence(__ATOMIC_SEQ_CST);
  }
  __syncthreads();
}

// ---------------------------------------------------------------------------
// prep: wcat rows [0,512)=Wa, [512,2048)=Whh, [2048,2560)=Wout; wih raw; enc8.
// ---------------------------------------------------------------------------
__global__ void __launch_bounds__(256) prep_kernel(
    const float* __restrict__ Wa, const float* __restrict__ Whh,
    const float* __restrict__ Wout, const float* __restrict__ Wih,
    const float* __restrict__ enc,
    unsigned short* __restrict__ wcat, unsigned short* __restrict__ wihb,
    unsigned char* __restrict__ enc8, int use_enc8) {
  const size_t gid = (size_t)blockIdx.x * 256 + threadIdx.x;
  const size_t stride = (size_t)gridDim.x * 256;
  for (size_t i = gid; i < 2097152u; i += stride) {
    float v; unsigned short* d;
    if (i < 262144u)       { v = Wa[i];              d = wcat + i; }
    else if (i < 1048576u) { v = Whh[i - 262144u];   d = wcat + i; }
    else if (i < 1310720u) { v = Wout[i - 1048576u]; d = wcat + i; }
    else                   { v = Wih[i - 1310720u];  d = wihb + (i - 1310720u); }
    *d = f2bf(v);
  }
  if (use_enc8) {
    for (size_t j = gid; j < 4194304u; j += stride) {
      float2 e = ((const float2*)enc)[j];
      int pk = __builtin_amdgcn_cvt_pk_fp8_f32(e.x, e.y, 0, false);
      ((unsigned short*)enc8)[j] = (unsigned short)(pk & 0xffff);
    }
  }
}

// ---------------------------------------------------------------------------
// keysT[b][h][s] = exp(2*(enc[b,s]·Ua[h] + bu[h]))  (bf16, transposed store)
// ---------------------------------------------------------------------------
__global__ void __launch_bounds__(256) keys_kernel(
    const float* __restrict__ enc, const float* __restrict__ Ua,
    const float* __restrict__ bu, unsigned short* __restrict__ keysT) {
  const int tid = threadIdx.x;
  const int w = tid >> 6, lane = tid & 63, ln = lane & 15, kq = lane >> 4;
  const int mb = blockIdx.x >> 3, nb = blockIdx.x & 7;
  const int mrow = mb * 64 + w * 16 + ln;
  f4v acc[4] = {{0,0,0,0},{0,0,0,0},{0,0,0,0},{0,0,0,0}};
  for (int ks = 0; ks < 16; ++ks) {
    const float* ap = enc + (size_t)mrow * 512 + ks * 32 + kq * 8;
    s8v af;
#pragma unroll
    for (int j = 0; j < 8; ++j) af[j] = (short)f2bf(ap[j]);
#pragma unroll
    for (int nt = 0; nt < 4; ++nt) {
      int n = nb * 64 + nt * 16 + ln;
      const float* up = Ua + (size_t)n * 512 + ks * 32 + kq * 8;
      s8v bf;
#pragma unroll
      for (int j = 0; j < 8; ++j) bf[j] = (short)f2bf(up[j]);
      acc[nt] = mfma16(af, bf, acc[nt]);
    }
  }
#pragma unroll
  for (int nt = 0; nt < 4; ++nt) {
    int n = nb * 64 + nt * 16 + ln;
    float bias = bu[n];
#pragma unroll
    for (int r = 0; r < 4; ++r) {
      int gm = mb * 64 + w * 16 + kq * 4 + r;
      int bb = gm >> 8, ss = gm & 255;
      keysT[(size_t)bb * 131072u + (size_t)n * 256 + ss] =
          f2bf(__expf(2.f * (acc[nt][r] + bias)));
    }
  }
}

// ---------------------------------------------------------------------------
// persistent decoder: 64 blocks x 512 threads
// ---------------------------------------------------------------------------
__global__ void __launch_bounds__(512, 1) decoder_kernel(
    const float* __restrict__ enc, const float* __restrict__ ba_,
    const float* __restrict__ va_, const float* __restrict__ bih_,
    const float* __restrict__ bhh_, const float* __restrict__ bout_,
    const unsigned short* __restrict__ wcat, const unsigned short* __restrict__ wihb,
    const unsigned short* __restrict__ keysT, const unsigned char* __restrict__ enc8,
    unsigned* __restrict__ bar, unsigned short* __restrict__ hbf,
    float* __restrict__ qbuf, float* __restrict__ ghb,
    unsigned short* __restrict__ ctxg, float* __restrict__ out, int use_enc8) {
  const int bid = blockIdx.x, tid = threadIdx.x;
  const int w = tid >> 6, lane = tid & 63, ln = lane & 15, kq = lane >> 4;
  const int ab = (bid & 7) * 8 + (bid >> 3);     // attention batch (XCD-stable)

  float* logits = out + OUT_LOGITS;
  float* hfin   = out + OUT_HFIN;
  float* attn   = out + OUT_ATTN;

  __shared__ u64 hsw[8192];                      // 64KB swizzled h (P1)
  __shared__ float2 evL[512];                    // {Eq, va}
  __shared__ float swL[256];
  __shared__ float ZpL[8];
  __shared__ float cpart[2][256][2];
  __shared__ float hofL[64 * 20];                // h f32, P3-persistent, padded
  __shared__ float naccf[4 * 16 * 20];           // gate-n exchange, padded

  unsigned gen = 0;
  const float va_r = va_[tid];

  for (int i = tid; i < 64 * 20; i += 512) hofL[i] = 0.f;
  // vasum
  {
    float vs = va_r;
#pragma unroll
    for (int off = 32; off > 0; off >>= 1) vs += __shfl_xor(vs, off, 64);
    if (lane == 0) ZpL[w] = vs;
  }
  __syncthreads();
  float vasum = 0.f;
#pragma unroll
  for (int l = 0; l < 8; ++l) vasum += ZpL[l];
  __syncthreads();

  // ---- P1 loop-invariants: wave wg owns output col-tile wg (160 tiles) ----
  const int wg = bid * 8 + w;
  const int wgc = (wg < 160) ? wg : 159;
  const int p1rg = (wg < 32) ? 0 : (wg < 128) ? 1 : (wg < 160) ? 2 : 3;
  const int p1colbase = (p1rg == 0) ? wg * 16
                       : (p1rg == 1) ? (wg - 32) * 16
                       : (wgc - 128) * 16;
  const int p1col = p1colbase + ln;
  const s8v* p1wp = (const s8v*)(wcat + (size_t)(wgc * 16 + ln) * 512);
  float p1bias = 0.f;
  if (p1rg == 0)      p1bias = ba_[p1col];
  else if (p1rg == 1) p1bias = bhh_[p1col];
  else if (p1rg == 2) p1bias = bout_[p1col];

  // ---- P3 loop-invariants: block m owns h-cols [16m,16m+16) --------------
  const int mcl = (bid < 32) ? bid : 0;
  const int m16 = mcl * 16;
  const int wq = w & 3, gd = w >> 2;
  const int p3b = wq * 16 + ln;                  // batch handled by this lane
  const s8v* wrp = (const s8v*)(wihb + (size_t)(m16 + ln) * 512);
  const s8v* wzp = (const s8v*)(wihb + (size_t)(512 + m16 + ln) * 512);
  const s8v* wnp = (const s8v*)(wihb + (size_t)(1024 + m16 + ln) * 512);
  float bihv[3][4];
#pragma unroll
  for (int g = 0; g < 3; ++g)
#pragma unroll
    for (int r = 0; r < 4; ++r) bihv[g][r] = bih_[g * 512 + m16 + kq * 4 + r];

  const unsigned short* kb = keysT + (size_t)ab * 131072u;
  const unsigned char* e8p = enc8 + (size_t)ab * 131072u;

#pragma clang loop unroll(disable)
  for (int it = 0; it <= 256; ++it) {
    // ================= P1: [q|gh|logits_{it-1}] = h @ Wcat^T ===============
    if (bid < 20) {
      const u64* hb64 = (const u64*)hbf;
      u64 tv[16];
#pragma unroll
      for (int k = 0; k < 16; ++k) tv[k] = cload64(hb64 + (k << 9) + tid);
#pragma unroll
      for (int k = 0; k < 16; ++k) {
        int j = (k << 9) + tid;
        int row = j >> 7, col8 = j & 127;
        int sw = (col8 >> 1) ^ (row & 7);
        hsw[row * 128 + sw * 2 + (col8 & 1)] = tv[k];
      }
      __syncthreads();
      const bool active = !((p1rg == 2 && it == 0) || (p1rg != 2 && it == 256));
      if (active) {
        f4v acc[4] = {{0,0,0,0},{0,0,0,0},{0,0,0,0},{0,0,0,0}};
#pragma unroll
        for (int ks = 0; ks < 16; ++ks) {
          s8v bfrag = p1wp[ks * 4 + kq];
#pragma unroll
          for (int mt = 0; mt < 4; ++mt) {
            int row = mt * 16 + ln;
            s8v afrag = *((const s8v*)hsw + row * 64 + ((ks * 4 + kq) ^ (row & 7)));
            acc[mt] = mfma16(afrag, bfrag, acc[mt]);
          }
        }
#pragma unroll
        for (int mt = 0; mt < 4; ++mt)
#pragma unroll
          for (int r = 0; r < 4; ++r) {
            int b = mt * 16 + kq * 4 + r;
            float v = acc[mt][r] + p1bias;
            if (p1rg == 0)
              cstore(qbuf + (size_t)b * 512 + p1col, v);
            else if (p1rg == 1)
              cstore(ghb + (size_t)b * 1536 + p1col, v);
            else
              cstore(logits + (size_t)(it - 1) * 32768 + (size_t)b * 512 + p1col, v);
          }
      }
      __syncthreads();          // protect hsw before next-iter restage
    }
    gbar(bar, gen);
    if (it == 256) break;

    // ================= P2: attention (1 block per batch) ===================
    {
      float qv = cload(qbuf + (size_t)ab * 512 + tid);
      float2 ev; ev.x = __expf(2.f * qv); ev.y = va_r;
      evL[tid] = ev;
    }
    __syncthreads();
    {
      const int s = w * 32 + (lane & 31);
      const int h0 = (lane >> 5) * 256;
      const unsigned short* kp = kb + (size_t)h0 * 256 + s;
      float a2 = 0.f;
#pragma unroll 8
      for (int h = 0; h < 256; ++h) {
        float2 ev = evL[h0 + h];
        float Ek = bf2f(kp[(size_t)h * 256]);
        a2 += ev.y * __builtin_amdgcn_rcpf(1.f + ev.x * Ek);
      }
      a2 += __shfl_xor(a2, 32, 64);
      float wt = __expf(vasum - 2.f * a2);
      float zp = wt;
#pragma unroll
      for (int off = 16; off > 0; off >>= 1) zp += __shfl_xor(zp, off, 64);
      if (lane < 32) { swL[s] = wt; if (lane == 0) ZpL[w] = zp; }
    }
    __syncthreads();
    float Z = 0.f;
#pragma unroll
    for (int l = 0; l < 8; ++l) Z += ZpL[l];
    float invZ = __builtin_amdgcn_rcpf(Z);
    {
      const int hp = tid & 255, sh = tid >> 8;
      const int s0 = sh * 128;
      float c0 = 0.f, c1 = 0.f;
      if (use_enc8) {
        const unsigned char* ep = e8p + (size_t)s0 * 512 + hp * 2;
#pragma unroll 8
        for (int i = 0; i < 128; ++i) {
          float wt = swL[s0 + i];
          unsigned short v8 = *(const unsigned short*)(ep + (size_t)i * 512);
          f2v ef = __builtin_amdgcn_cvt_pk_f32_fp8((int)v8, false);
          c0 += wt * ef[0]; c1 += wt * ef[1];
        }
      } else {
        const float2* ep = (const float2*)(enc + (size_t)(ab * 256 + s0) * 512) + hp;
#pragma unroll 8
        for (int i = 0; i < 128; ++i) {
          float wt = swL[s0 + i];
          float2 e = ep[(size_t)i * 256];
          c0 += wt * e.x; c1 += wt * e.y;
        }
      }
      cpart[sh][hp][0] = c0; cpart[sh][hp][1] = c1;
    }
    __syncthreads();
    if (tid < 256) {
      float cc0 = (cpart[0][tid][0] + cpart[1][tid][0]) * invZ;
      float cc1 = (cpart[0][tid][1] + cpart[1][tid][1]) * invZ;
      unsigned pk = (unsigned)f2bf(cc0) | ((unsigned)f2bf(cc1) << 16);
      cstoreu((unsigned*)ctxg + (size_t)ab * 256 + tid, pk);
      attn[(size_t)ab * 65536 + (size_t)it * 256 + tid] = swL[tid] * invZ;
    }
    gbar(bar, gen);

    // ================= P3: gi = Wih.ctx (full K) + GRU =====================
    if (bid < 32) {
      const u64* cx = (const u64*)ctxg + (size_t)p3b * 128;
      u64 t[32];
#pragma unroll
      for (int ks = 0; ks < 16; ++ks) {
        t[2 * ks]     = cload64(cx + ks * 8 + kq * 2);
        t[2 * ks + 1] = cload64(cx + ks * 8 + kq * 2 + 1);
      }
      float tgh[3][4];
      if (gd == 0) {
        const float* gb = ghb + (size_t)p3b * 1536 + m16 + kq * 4;
#pragma unroll
        for (int g = 0; g < 3; ++g)
#pragma unroll
          for (int r = 0; r < 4; ++r) tgh[g][r] = cload(gb + g * 512 + r);
      }
      f4v arS = {0,0,0,0}, azS = {0,0,0,0};
      if (gd == 1) {
        f4v an = {0,0,0,0};
#pragma unroll
        for (int ks = 0; ks < 16; ++ks) {
          union { u64 u[2]; s8v v; } bu2;
          bu2.u[0] = t[2 * ks]; bu2.u[1] = t[2 * ks + 1];
          an = mfma16(wnp[ks * 4 + kq], bu2.v, an);
        }
        *(f4v*)&naccf[(wq * 16 + ln) * 20 + kq * 4] = an;
      } else {
#pragma unroll
        for (int ks = 0; ks < 16; ++ks) {
          union { u64 u[2]; s8v v; } bu2;
          bu2.u[0] = t[2 * ks]; bu2.u[1] = t[2 * ks + 1];
          arS = mfma16(wrp[ks * 4 + kq], bu2.v, arS);
          azS = mfma16(wzp[ks * 4 + kq], bu2.v, azS);
        }
      }
      __syncthreads();
      if (gd == 0) {
        float hn[4];
#pragma unroll
        for (int r = 0; r < 4; ++r) {
          float anr = naccf[(wq * 16 + ln) * 20 + kq * 4 + r];
          float rr = sigm(arS[r] + bihv[0][r] + tgh[0][r]);
          float zz = sigm(azS[r] + bihv[1][r] + tgh[1][r]);
          float nn = tanh2(anr + bihv[2][r] + rr * tgh[2][r]);
          float ho = hofL[p3b * 20 + kq * 4 + r];
          hn[r] = (1.f - zz) * nn + zz * ho;
          hofL[p3b * 20 + kq * 4 + r] = hn[r];
        }
        union { unsigned short s[4]; u64 u; } hb4;
#pragma unroll
        for (int r = 0; r < 4; ++r) hb4.s[r] = f2bf(hn[r]);
        cstore64((u64*)(hbf + (size_t)p3b * 512 + m16 + kq * 4), hb4.u);
        if (it == 255) {
#pragma unroll
          for (int r = 0; r < 4; ++r)
            hfin[(size_t)p3b * 512 + m16 + kq * 4 + r] = hn[r];
        }
      }
      __syncthreads();          // protect naccf before next iteration
    }
    gbar(bar, gen);
  }

  // -------- final: log_softmax over logits rows (bias already applied) -----
#pragma clang loop unroll(disable)
  for (int i = 0; i < 32; ++i) {
    int row = bid * 256 + w * 32 + i;
    const u64* xr64 = (const u64*)(logits + (size_t)row * 512) + lane * 4;
    u64 t4[4];
#pragma unroll
    for (int j = 0; j < 4; ++j) t4[j] = cload64(xr64 + j);
    union { u64 u[4]; float f[8]; } xu;
#pragma unroll
    for (int j = 0; j < 4; ++j) xu.u[j] = t4[j];
    float mx = xu.f[0];
#pragma unroll
    for (int j = 1; j < 8; ++j) mx = fmaxf(mx, xu.f[j]);
#pragma unroll
    for (int off = 32; off > 0; off >>= 1) mx = fmaxf(mx, __shfl_xor(mx, off, 64));
    float sm = 0.f;
#pragma unroll
    for (int j = 0; j < 8; ++j) sm += __expf(xu.f[j] - mx);
#pragma unroll
    for (int off = 32; off > 0; off >>= 1) sm += __shfl_xor(sm, off, 64);
    float lse = mx + __logf(sm);
    float* xw = logits + (size_t)row * 512 + lane * 8;
    f4v o0, o1;
#pragma unroll
    for (int j = 0; j < 4; ++j) { o0[j] = xu.f[j] - lse; o1[j] = xu.f[4 + j] - lse; }
    ((f4v*)xw)[0] = o0;
    ((f4v*)xw)[1] = o1;
  }
}

// ---------------------------------------------------------------------------
extern "C" void kernel_launch(void* const* d_in, const int* in_sizes, int n_in,
                              void* d_out, int out_size, void* d_ws, size_t ws_size,
                              hipStream_t stream) {
  const float* enc  = (const float*)d_in[0];
  const float* Wa   = (const float*)d_in[1];
  const float* ba   = (const float*)d_in[2];
  const float* Ua   = (const float*)d_in[3];
  const float* bu   = (const float*)d_in[4];
  const float* Va   = (const float*)d_in[5];
  // d_in[6] = bv : softmax-invariant, unused
  const float* Wih  = (const float*)d_in[7];
  const float* bih  = (const float*)d_in[8];
  const float* Whh  = (const float*)d_in[9];
  const float* bhh  = (const float*)d_in[10];
  const float* Wout = (const float*)d_in[11];
  const float* bout = (const float*)d_in[12];
  (void)in_sizes; (void)n_in; (void)out_size;

  char* ws = (char*)d_ws;
  unsigned*       bar   = (unsigned*)(ws + OFF_BAR);
  unsigned short* hbf   = (unsigned short*)(ws + OFF_HBF);
  float*          qbuf  = (float*)(ws + OFF_Q);
  float*          ghb   = (float*)(ws + OFF_GH);
  unsigned short* ctxg  = (unsigned short*)(ws + OFF_CTX);
  unsigned short* wcat  = (unsigned short*)(ws + OFF_WCAT);
  unsigned short* wihb  = (unsigned short*)(ws + OFF_WIH);
  unsigned short* keysT = (unsigned short*)(ws + OFF_KEYS);
  unsigned char*  enc8  = (unsigned char*)(ws + OFF_ENC8);
  int use_enc8 = (ws_size >= (size_t)WS_FULL) ? 1 : 0;

  hipMemsetAsync(d_ws, 0, MEMSET_BYTES, stream);       // barrier + h0 = 0
  prep_kernel<<<1024, 256, 0, stream>>>(Wa, Whh, Wout, Wih, enc,
                                        wcat, wihb, enc8, use_enc8);
  keys_kernel<<<2048, 256, 0, stream>>>(enc, Ua, bu, keysT);
  decoder_kernel<<<64, 512, 0, stream>>>(enc, ba, Va, bih, bhh, bout,
                                         wcat, wihb, keysT, enc8,
                                         bar, hbf, qbuf, ghb, ctxg,
                                         (float*)d_out, use_enc8);
}

// Round 3
// 12413.300 us; speedup vs baseline: 1.5992x; 1.5992x over previous
//
#include <hip/hip_runtime.h>

// ============================================================================
// AttnDecoderRNN round 8: batches are INDEPENDENT -> 8 independent groups of
// 8 blocks (group g = blocks {bid: bid&7==g}, batches [8g,8g+8)).  No global
// barrier; 2 per-group 8-arrival barriers/step.  P3 GEMM deleted via
// precomputed encP[b,s,:] = Wih.enc[b,s]+bih (fp8):
//   gi = (sum_s w_s * encP[b,s,:]) / Z   (linearity of Wih).
//   P1 (8 blk/group): [q+ba | gh+bhh | logits+bout] = h @ Wcat^T, 320 cols/blk,
//       MFMA M=16 (8 real batch rows), h staged from 8KB LLC read into LDS.
//   P2 (1 blk/batch): R5-style coalesced score loop (s8v keys + shfl reduce),
//       per-wave gi partials over 32 s each, GRU local; h lives in LDS.
// Zero atomics, single writer per address, R5-proven LLC load/store batching.
// ============================================================================

typedef short s8v __attribute__((ext_vector_type(8)));
typedef float f4v __attribute__((ext_vector_type(4)));
typedef float f2v __attribute__((ext_vector_type(2)));
typedef unsigned long long u64;

// ws byte offsets
#define OFF_BAR   0u
#define OFF_HBF   4096u        // [8][16][512] bf16 (rows 8-15 always 0)
#define OFF_Q     135168u      // [64][512] f32  (q + ba)
#define OFF_GH    266240u      // [64][1536] f32 (gh + bhh)
#define OFF_WCAT  659456u      // [2560][512] bf16 : Wa | Whh | Wout
#define OFF_KEYS  3280896u     // [64*256][512] bf16 : Ek = exp(2*(Ua.enc+bu))
#define OFF_ENCP  20058112u    // [64*256][1536] fp8 : Wih.enc + bih
#define WS_FULL   45223936u
#define MEMSET_BYTES 135168u   // bar + hbf

// d_out offsets (floats)
#define OUT_HFIN   8388608u
#define OUT_ATTN   8421376u

__device__ __forceinline__ unsigned short f2bf(float f) {
  union { float f; unsigned u; } a; a.f = f;
  unsigned r = a.u + 0x7fffu + ((a.u >> 16) & 1u);
  return (unsigned short)(r >> 16);
}
__device__ __forceinline__ float bf2f(unsigned short h) {
  union { unsigned u; float f; } a; a.u = (unsigned)h << 16; return a.f;
}
__device__ __forceinline__ float cload(const float* p) {
  return __hip_atomic_load(p, __ATOMIC_RELAXED, __HIP_MEMORY_SCOPE_AGENT);
}
__device__ __forceinline__ void cstore(float* p, float v) {
  __hip_atomic_store(p, v, __ATOMIC_RELAXED, __HIP_MEMORY_SCOPE_AGENT);
}
__device__ __forceinline__ void cstoreu(unsigned* p, unsigned v) {
  __hip_atomic_store(p, v, __ATOMIC_RELAXED, __HIP_MEMORY_SCOPE_AGENT);
}
__device__ __forceinline__ u64 cload64(const u64* p) {
  return __hip_atomic_load(p, __ATOMIC_RELAXED, __HIP_MEMORY_SCOPE_AGENT);
}
__device__ __forceinline__ float sigm(float x) {
  return __builtin_amdgcn_rcpf(1.f + __expf(-x));
}
__device__ __forceinline__ float tanh2(float x) {
  return 1.f - 2.f * __builtin_amdgcn_rcpf(1.f + __expf(x + x));
}
__device__ __forceinline__ f4v mfma16(s8v a, s8v b, f4v c) {
  return __builtin_amdgcn_mfma_f32_16x16x32_bf16(a, b, c, 0, 0, 0);
}

// per-group 8-arrival barrier: counter & flag on separate 64B lines
__device__ __forceinline__ void gbar(unsigned* cnt, unsigned* flag, unsigned& gen) {
  asm volatile("s_waitcnt vmcnt(0) lgkmcnt(0)" ::: "memory");
  __syncthreads();
  if (threadIdx.x == 0) {
    __atomic_signal_fence(__ATOMIC_SEQ_CST);
    gen++;
    unsigned old = __hip_atomic_fetch_add(cnt, 1u, __ATOMIC_RELAXED,
                                          __HIP_MEMORY_SCOPE_AGENT);
    if (old == gen * 8u - 1u)
      __hip_atomic_store(flag, gen, __ATOMIC_RELAXED, __HIP_MEMORY_SCOPE_AGENT);
    while (__hip_atomic_load(flag, __ATOMIC_RELAXED,
                             __HIP_MEMORY_SCOPE_AGENT) < gen)
      __builtin_amdgcn_s_sleep(1);
    __atomic_signal_fence(__ATOMIC_SEQ_CST);
  }
  __syncthreads();
}

// ---------------------------------------------------------------------------
// prep: wcat = [Wa|Whh|Wout] bf16
// ---------------------------------------------------------------------------
__global__ void __launch_bounds__(256) prep_kernel(
    const float* __restrict__ Wa, const float* __restrict__ Whh,
    const float* __restrict__ Wout, unsigned short* __restrict__ wcat) {
  const size_t gid = (size_t)blockIdx.x * 256 + threadIdx.x;
  const size_t stride = (size_t)gridDim.x * 256;
  for (size_t i = gid; i < 1310720u; i += stride) {
    float v;
    if (i < 262144u)       v = Wa[i];
    else if (i < 1048576u) v = Whh[i - 262144u];
    else                   v = Wout[i - 1048576u];
    wcat[i] = f2bf(v);
  }
}

// ---------------------------------------------------------------------------
// keys[b*256+s][h] = exp(2*(enc[b,s]·Ua[h] + bu[h]))  (bf16)
// ---------------------------------------------------------------------------
__global__ void __launch_bounds__(256) keys_kernel(
    const float* __restrict__ enc, const float* __restrict__ Ua,
    const float* __restrict__ bu, unsigned short* __restrict__ keysb) {
  const int tid = threadIdx.x;
  const int w = tid >> 6, lane = tid & 63, ln = lane & 15, kq = lane >> 4;
  const int mb = blockIdx.x >> 3, nb = blockIdx.x & 7;
  const int mrow = mb * 64 + w * 16 + ln;
  f4v acc[4] = {{0,0,0,0},{0,0,0,0},{0,0,0,0},{0,0,0,0}};
  for (int ks = 0; ks < 16; ++ks) {
    const float* ap = enc + (size_t)mrow * 512 + ks * 32 + kq * 8;
    s8v af;
#pragma unroll
    for (int j = 0; j < 8; ++j) af[j] = (short)f2bf(ap[j]);
#pragma unroll
    for (int nt = 0; nt < 4; ++nt) {
      int n = nb * 64 + nt * 16 + ln;
      const float* up = Ua + (size_t)n * 512 + ks * 32 + kq * 8;
      s8v bf;
#pragma unroll
      for (int j = 0; j < 8; ++j) bf[j] = (short)f2bf(up[j]);
      acc[nt] = mfma16(af, bf, acc[nt]);
    }
  }
#pragma unroll
  for (int nt = 0; nt < 4; ++nt) {
    int n = nb * 64 + nt * 16 + ln;
    float bias = bu[n];
#pragma unroll
    for (int r = 0; r < 4; ++r) {
      int gm = mb * 64 + w * 16 + kq * 4 + r;
      keysb[(size_t)gm * 512 + n] = f2bf(__expf(2.f * (acc[nt][r] + bias)));
    }
  }
}

// ---------------------------------------------------------------------------
// encP[b*256+s][n] = fp8(enc[b,s]·Wih[n] + bih[n]),  n<1536
// ---------------------------------------------------------------------------
__global__ void __launch_bounds__(256) encp_kernel(
    const float* __restrict__ enc, const float* __restrict__ Wih,
    const float* __restrict__ bih, unsigned char* __restrict__ encp) {
  const int tid = threadIdx.x;
  const int w = tid >> 6, lane = tid & 63, ln = lane & 15, kq = lane >> 4;
  const int mb = blockIdx.x, nb = blockIdx.y;
  const int mrow = mb * 64 + w * 16 + ln;
  f4v acc[4] = {{0,0,0,0},{0,0,0,0},{0,0,0,0},{0,0,0,0}};
  for (int ks = 0; ks < 16; ++ks) {
    const float* ap = enc + (size_t)mrow * 512 + ks * 32 + kq * 8;
    s8v af;
#pragma unroll
    for (int j = 0; j < 8; ++j) af[j] = (short)f2bf(ap[j]);
#pragma unroll
    for (int nt = 0; nt < 4; ++nt) {
      int n = nb * 64 + nt * 16 + ln;
      const float* up = Wih + (size_t)n * 512 + ks * 32 + kq * 8;
      s8v bf;
#pragma unroll
      for (int j = 0; j < 8; ++j) bf[j] = (short)f2bf(up[j]);
      acc[nt] = mfma16(af, bf, acc[nt]);
    }
  }
#pragma unroll
  for (int nt = 0; nt < 4; ++nt) {
    int n = nb * 64 + nt * 16 + ln;
    float bias = bih[n];
#pragma unroll
    for (int r = 0; r < 4; ++r) {
      int gm = mb * 64 + w * 16 + kq * 4 + r;
      float v = acc[nt][r] + bias;
      int pk = __builtin_amdgcn_cvt_pk_fp8_f32(v, v, 0, false);
      encp[(size_t)gm * 1536 + n] = (unsigned char)(pk & 0xff);
    }
  }
}

// ---------------------------------------------------------------------------
// persistent decoder: 64 blocks x 512 threads, 8 independent groups of 8
// ---------------------------------------------------------------------------
__global__ void __launch_bounds__(512, 1) decoder_kernel(
    const float* __restrict__ ba_, const float* __restrict__ va_,
    const float* __restrict__ bhh_, const float* __restrict__ bout_,
    const unsigned short* __restrict__ wcat, const unsigned short* __restrict__ keysb,
    const unsigned char* __restrict__ encp, unsigned* __restrict__ bar,
    unsigned short* __restrict__ hbf, float* __restrict__ qst,
    float* __restrict__ ghst, float* __restrict__ out) {
  const int bid = blockIdx.x, tid = threadIdx.x;
  const int w = tid >> 6, lane = tid & 63, ln = lane & 15, kq = lane >> 4;
  const int g = bid & 7, j = bid >> 3;           // group, slot
  const int b = g * 8 + j;                       // this block's P2 batch

  float* logits = out;
  float* hfin   = out + OUT_HFIN;
  float* attn   = out + OUT_ATTN;

  __shared__ unsigned short hA[16][520];         // P1 h stage (padded rows)
  __shared__ float biasL[320];
  __shared__ float evq[512];
  __shared__ float swL[256];
  __shared__ float ZpL[8];
  __shared__ float gp[8][1536];                  // per-wave gi partials
  __shared__ float hL[512];                      // this batch's h (persistent)

  unsigned gen = 0;
  unsigned* gcnt  = bar + g * 64;
  unsigned* gflag = bar + g * 64 + 16;

  // loop invariants -------------------------------------------------------
  float vav[8];
  float vasum;
  {
    float vs = 0.f;
#pragma unroll
    for (int jj = 0; jj < 8; ++jj) { vav[jj] = va_[lane * 8 + jj]; vs += vav[jj]; }
#pragma unroll
    for (int off = 32; off > 0; off >>= 1) vs += __shfl_xor(vs, off, 64);
    vasum = vs;
  }
  if (tid < 320) {
    int col = j * 320 + tid;
    biasL[tid] = (col < 512) ? ba_[col]
               : (col < 2048) ? bhh_[col - 512] : bout_[col - 2048];
  }
  hL[tid] = 0.f;
  for (int i2 = tid; i2 < 8 * 130; i2 += 512)    // zero hA rows 8-15 (forever)
    *((u64*)&hA[0][0] + 8 * 130 + i2) = 0ull;
  __syncthreads();

#pragma clang loop unroll(disable)
  for (int it = 0; it <= 256; ++it) {
    // ============ P1: [q|gh|logits_{it-1}] = h @ Wcat^T (320 cols) =========
    {
      const u64* hb = (const u64*)hbf + (size_t)g * 2048;
      u64 t0 = cload64(hb + tid), t1 = cload64(hb + 512 + tid);
      {
        int r0 = tid >> 7, c0 = tid & 127;
        *((u64*)&hA[0][0] + r0 * 130 + c0) = t0;
        int i1 = 512 + tid, r1 = i1 >> 7, c1 = i1 & 127;
        *((u64*)&hA[0][0] + r1 * 130 + c1) = t1;
      }
    }
    __syncthreads();
#pragma clang loop unroll(disable)
    for (int u = w; u < 20; u += 8) {
      int C0 = j * 320 + u * 16;
      bool isLog = (C0 >= 2048);
      if ((isLog && it == 0) || (!isLog && it == 256)) continue;
      const s8v* wp = (const s8v*)(wcat + (size_t)(C0 + ln) * 512);
      f4v acc = {0.f, 0.f, 0.f, 0.f};
#pragma unroll
      for (int ks = 0; ks < 16; ++ks) {
        s8v af = *(const s8v*)&hA[ln][ks * 32 + kq * 8];
        acc = mfma16(af, wp[ks * 4 + kq], acc);
      }
      if (kq < 2) {                              // rows 8-15 are padding
        int col = C0 + ln;
        float bias = biasL[u * 16 + ln];
#pragma unroll
        for (int r = 0; r < 4; ++r) {
          int gb = g * 8 + kq * 4 + r;           // global batch
          float v = acc[r] + bias;
          if (C0 < 512)
            cstore(qst + (size_t)gb * 512 + col, v);
          else if (C0 < 2048)
            cstore(ghst + (size_t)gb * 1536 + (col - 512), v);
          else
            cstore(logits + (size_t)(it - 1) * 32768 + (size_t)gb * 512 + (col - 2048), v);
        }
      }
    }
    gbar(gcnt, gflag, gen);
    if (it == 256) break;

    // ============ P2: attention + gi + GRU (this block's batch) ============
    float gr_h, gz_h, gn_h;
    {
      float qv = cload(qst + (size_t)b * 512 + tid);
      gr_h = cload(ghst + (size_t)b * 1536 + tid);
      gz_h = cload(ghst + (size_t)b * 1536 + 512 + tid);
      gn_h = cload(ghst + (size_t)b * 1536 + 1024 + tid);
      evq[tid] = __expf(2.f * qv);
    }
    __syncthreads();
    float eq[8];
#pragma unroll
    for (int jj = 0; jj < 8; ++jj) eq[jj] = evq[lane * 8 + jj];
    // scores: wave w handles s in [w*32, w*32+32)
    {
      const unsigned short* kbase = keysb + ((size_t)b * 256 + w * 32) * 512 + lane * 8;
      float zacc = 0.f;
#pragma unroll 4
      for (int i = 0; i < 32; ++i) {
        s8v kv = *(const s8v*)(kbase + (size_t)i * 512);
        float a2 = 0.f;
#pragma unroll
        for (int jj = 0; jj < 8; ++jj) {
          float P = eq[jj] * bf2f((unsigned short)kv[jj]);
          a2 += vav[jj] * __builtin_amdgcn_rcpf(1.f + P);
        }
#pragma unroll
        for (int off = 32; off > 0; off >>= 1) a2 += __shfl_xor(a2, off, 64);
        float wt = __expf(vasum - 2.f * a2);
        if (lane == 0) swL[w * 32 + i] = wt;
        zacc += wt;
      }
      if (lane == 0) ZpL[w] = zacc;
    }
    __syncthreads();
    float Z = 0.f;
#pragma unroll
    for (int l = 0; l < 8; ++l) Z += ZpL[l];
    float invZ = __builtin_amdgcn_rcpf(Z);
    // gi partials: wave w sums its 32 s rows of encP (lane owns 24 dims)
    {
      const unsigned char* pe = encp + ((size_t)b * 256 + w * 32) * 1536 + (size_t)lane * 24;
      float ga[24];
#pragma unroll
      for (int k = 0; k < 24; ++k) ga[k] = 0.f;
#pragma unroll 4
      for (int i = 0; i < 32; ++i) {
        float wt = swL[w * 32 + i];
        const u64* p64 = (const u64*)(pe + (size_t)i * 1536);
        u64 d0 = p64[0], d1 = p64[1], d2 = p64[2];
#define UNPK(dd, base) { \
        union { u64 u; unsigned x[2]; } uu; uu.u = (dd); \
        f2v f0 = __builtin_amdgcn_cvt_pk_f32_fp8((int)uu.x[0], false); \
        f2v f1 = __builtin_amdgcn_cvt_pk_f32_fp8((int)uu.x[0], true);  \
        f2v f2 = __builtin_amdgcn_cvt_pk_f32_fp8((int)uu.x[1], false); \
        f2v f3 = __builtin_amdgcn_cvt_pk_f32_fp8((int)uu.x[1], true);  \
        ga[(base)+0] += wt * f0[0]; ga[(base)+1] += wt * f0[1]; \
        ga[(base)+2] += wt * f1[0]; ga[(base)+3] += wt * f1[1]; \
        ga[(base)+4] += wt * f2[0]; ga[(base)+5] += wt * f2[1]; \
        ga[(base)+6] += wt * f3[0]; ga[(base)+7] += wt * f3[1]; }
        UNPK(d0, 0) UNPK(d1, 8) UNPK(d2, 16)
#undef UNPK
      }
      float* gpp = &gp[w][lane * 24];
#pragma unroll
      for (int q4 = 0; q4 < 6; ++q4)
        *(f4v*)(gpp + q4 * 4) = *(const f4v*)&ga[q4 * 4];
    }
    __syncthreads();
    // reduce partials + GRU: thread tid owns h-dim tid
    {
      float s0 = 0.f, s1 = 0.f, s2 = 0.f;
#pragma unroll
      for (int ww = 0; ww < 8; ++ww) {
        s0 += gp[ww][tid]; s1 += gp[ww][tid + 512]; s2 += gp[ww][tid + 1024];
      }
      float rr = sigm(s0 * invZ + gr_h);
      float zz = sigm(s1 * invZ + gz_h);
      float nn = tanh2(s2 * invZ + rr * gn_h);
      float hn = (1.f - zz) * nn + zz * hL[tid];
      hL[tid] = hn;
      if (it == 255) hfin[(size_t)b * 512 + tid] = hn;
      if (tid < 256) attn[(size_t)b * 65536 + (size_t)it * 256 + tid] = swL[tid] * invZ;
    }
    __syncthreads();
    if (tid < 256) {
      unsigned pk = (unsigned)f2bf(hL[2 * tid]) | ((unsigned)f2bf(hL[2 * tid + 1]) << 16);
      cstoreu((unsigned*)hbf + ((size_t)g * 16 + j) * 256 + tid, pk);
    }
    gbar(gcnt, gflag, gen);
  }

  // -------- finale: log_softmax on this block's batch rows (bias done) -----
#pragma clang loop unroll(disable)
  for (int i = 0; i < 32; ++i) {
    int row = (w * 32 + i) * 64 + b;
    const u64* xr64 = (const u64*)(logits + (size_t)row * 512) + lane * 4;
    u64 t4[4];
#pragma unroll
    for (int jj = 0; jj < 4; ++jj) t4[jj] = cload64(xr64 + jj);
    union { u64 u[4]; float f[8]; } xu;
#pragma unroll
    for (int jj = 0; jj < 4; ++jj) xu.u[jj] = t4[jj];
    float mx = xu.f[0];
#pragma unroll
    for (int jj = 1; jj < 8; ++jj) mx = fmaxf(mx, xu.f[jj]);
#pragma unroll
    for (int off = 32; off > 0; off >>= 1) mx = fmaxf(mx, __shfl_xor(mx, off, 64));
    float sm = 0.f;
#pragma unroll
    for (int jj = 0; jj < 8; ++jj) sm += __expf(xu.f[jj] - mx);
#pragma unroll
    for (int off = 32; off > 0; off >>= 1) sm += __shfl_xor(sm, off, 64);
    float lse = mx + __logf(sm);
    float* xw = logits + (size_t)row * 512 + lane * 8;
    f4v o0, o1;
#pragma unroll
    for (int jj = 0; jj < 4; ++jj) { o0[jj] = xu.f[jj] - lse; o1[jj] = xu.f[4 + jj] - lse; }
    ((f4v*)xw)[0] = o0;
    ((f4v*)xw)[1] = o1;
  }
}

// ---------------------------------------------------------------------------
extern "C" void kernel_launch(void* const* d_in, const int* in_sizes, int n_in,
                              void* d_out, int out_size, void* d_ws, size_t ws_size,
                              hipStream_t stream) {
  const float* enc  = (const float*)d_in[0];
  const float* Wa   = (const float*)d_in[1];
  const float* ba   = (const float*)d_in[2];
  const float* Ua   = (const float*)d_in[3];
  const float* bu   = (const float*)d_in[4];
  const float* Va   = (const float*)d_in[5];
  // d_in[6] = bv : softmax-invariant, unused
  const float* Wih  = (const float*)d_in[7];
  const float* bih  = (const float*)d_in[8];
  const float* Whh  = (const float*)d_in[9];
  const float* bhh  = (const float*)d_in[10];
  const float* Wout = (const float*)d_in[11];
  const float* bout = (const float*)d_in[12];
  (void)in_sizes; (void)n_in; (void)out_size; (void)ws_size;

  char* ws = (char*)d_ws;
  unsigned*       bar   = (unsigned*)(ws + OFF_BAR);
  unsigned short* hbf   = (unsigned short*)(ws + OFF_HBF);
  float*          qst   = (float*)(ws + OFF_Q);
  float*          ghst  = (float*)(ws + OFF_GH);
  unsigned short* wcat  = (unsigned short*)(ws + OFF_WCAT);
  unsigned short* keysb = (unsigned short*)(ws + OFF_KEYS);
  unsigned char*  encp  = (unsigned char*)(ws + OFF_ENCP);

  hipMemsetAsync(d_ws, 0, MEMSET_BYTES, stream);       // bar + hbf(h0=0)
  prep_kernel<<<512, 256, 0, stream>>>(Wa, Whh, Wout, wcat);
  keys_kernel<<<2048, 256, 0, stream>>>(enc, Ua, bu, keysb);
  encp_kernel<<<dim3(256, 24), 256, 0, stream>>>(enc, Wih, bih, encp);
  decoder_kernel<<<64, 512, 0, stream>>>(ba, Va, bhh, bout,
                                         wcat, keysb, encp, bar,
                                         hbf, qst, ghst, (float*)d_out);
}

// Round 5
// 11748.883 us; speedup vs baseline: 1.6896x; 1.0566x over previous
//
#include <hip/hip_runtime.h>

// ============================================================================
// AttnDecoderRNN round 10 = R9 with the group-base bug fixed.
// R9 post-mortem: P1 staged h from hbf with group stride g*512 u64 instead of
// g*1024 (hbf is [64][512] bf16 -> 128 u64/batch, 1024 u64/group).  Groups
// 1..7 read half-overlapped h -> absmax 0.53.  Also reverted Eq to f32 LDS
// (R9 stored bf16; unnecessary extra quantization on the score path).
//
// Structure (unchanged): 256 blocks (1/CU), 8 independent groups of 32
// (group = bid&7 -> XCD-local), 3 group-local 32-arrival barriers/step.
//   P1: 32 blocks split [q|gh+bhh|logits+bout] = h @ Wcat^T (5 tiles each).
//   P2: block p -> s-slice [8p,8p+8) scores for the group's 8 batches.
//   P3: block p owns h-cols [16p,16p+16): gi from TRANSPOSED encpT[b][n][s],
//       GRU local (h cols persist in LDS), attn out for its s-slice.
// Zero atomics, single writer per address.
// ============================================================================

typedef short s8v __attribute__((ext_vector_type(8)));
typedef float f4v __attribute__((ext_vector_type(4)));
typedef float f2v __attribute__((ext_vector_type(2)));
typedef unsigned long long u64;

// ws byte offsets
#define OFF_BAR    0u
#define OFF_HBF    4096u       // [64][512] bf16 h broadcast
#define OFF_Q      69632u      // [64][512] f32 (q + ba)
#define OFF_GH     200704u     // [64][1536] f32 (gh + bhh)
#define OFF_WB     593920u     // [64][256] f32 unnormalized softmax weights
#define OFF_WCAT   659456u     // [2560][512] bf16 : Wa | Whh | Wout
#define OFF_KEYS   3280896u    // [64*256][512] bf16 : Ek = exp(2*(Ua.enc+bu))
#define OFF_ENCPT  20058112u   // [64][1536][256] fp8 : (Wih.enc + bih)^T
#define WS_FULL    45223936u
#define MEMSET_BYTES 69632u    // bar + hbf

// d_out offsets (floats)
#define OUT_HFIN   8388608u
#define OUT_ATTN   8421376u

__device__ __forceinline__ unsigned short f2bf(float f) {
  union { float f; unsigned u; } a; a.f = f;
  unsigned r = a.u + 0x7fffu + ((a.u >> 16) & 1u);
  return (unsigned short)(r >> 16);
}
__device__ __forceinline__ float bf2f(unsigned short h) {
  union { unsigned u; float f; } a; a.u = (unsigned)h << 16; return a.f;
}
__device__ __forceinline__ float cload(const float* p) {
  return __hip_atomic_load(p, __ATOMIC_RELAXED, __HIP_MEMORY_SCOPE_AGENT);
}
__device__ __forceinline__ void cstore(float* p, float v) {
  __hip_atomic_store(p, v, __ATOMIC_RELAXED, __HIP_MEMORY_SCOPE_AGENT);
}
__device__ __forceinline__ void cstoreu(unsigned* p, unsigned v) {
  __hip_atomic_store(p, v, __ATOMIC_RELAXED, __HIP_MEMORY_SCOPE_AGENT);
}
__device__ __forceinline__ u64 cload64(const u64* p) {
  return __hip_atomic_load(p, __ATOMIC_RELAXED, __HIP_MEMORY_SCOPE_AGENT);
}
__device__ __forceinline__ float sigm(float x) {
  return __builtin_amdgcn_rcpf(1.f + __expf(-x));
}
__device__ __forceinline__ float tanh2(float x) {
  return 1.f - 2.f * __builtin_amdgcn_rcpf(1.f + __expf(x + x));
}
__device__ __forceinline__ f4v mfma16(s8v a, s8v b, f4v c) {
  return __builtin_amdgcn_mfma_f32_16x16x32_bf16(a, b, c, 0, 0, 0);
}

// per-group 32-arrival barrier: counter & flag on separate 64B lines
__device__ __forceinline__ void gbar(unsigned* cnt, unsigned* flag, unsigned& gen) {
  asm volatile("s_waitcnt vmcnt(0) lgkmcnt(0)" ::: "memory");
  __syncthreads();
  if (threadIdx.x == 0) {
    __atomic_signal_fence(__ATOMIC_SEQ_CST);
    gen++;
    unsigned old = __hip_atomic_fetch_add(cnt, 1u, __ATOMIC_RELAXED,
                                          __HIP_MEMORY_SCOPE_AGENT);
    if (old == gen * 32u - 1u)
      __hip_atomic_store(flag, gen, __ATOMIC_RELAXED, __HIP_MEMORY_SCOPE_AGENT);
    while (__hip_atomic_load(flag, __ATOMIC_RELAXED,
                             __HIP_MEMORY_SCOPE_AGENT) < gen)
      __builtin_amdgcn_s_sleep(1);
    __atomic_signal_fence(__ATOMIC_SEQ_CST);
  }
  __syncthreads();
}

// ---------------------------------------------------------------------------
// prep: wcat = [Wa|Whh|Wout] bf16
// ---------------------------------------------------------------------------
__global__ void __launch_bounds__(256) prep_kernel(
    const float* __restrict__ Wa, const float* __restrict__ Whh,
    const float* __restrict__ Wout, unsigned short* __restrict__ wcat) {
  const size_t gid = (size_t)blockIdx.x * 256 + threadIdx.x;
  const size_t stride = (size_t)gridDim.x * 256;
  for (size_t i = gid; i < 1310720u; i += stride) {
    float v;
    if (i < 262144u)       v = Wa[i];
    else if (i < 1048576u) v = Whh[i - 262144u];
    else                   v = Wout[i - 1048576u];
    wcat[i] = f2bf(v);
  }
}

// ---------------------------------------------------------------------------
// keys[b*256+s][h] = exp(2*(enc[b,s]·Ua[h] + bu[h]))  (bf16)
// ---------------------------------------------------------------------------
__global__ void __launch_bounds__(256) keys_kernel(
    const float* __restrict__ enc, const float* __restrict__ Ua,
    const float* __restrict__ bu, unsigned short* __restrict__ keysb) {
  const int tid = threadIdx.x;
  const int w = tid >> 6, lane = tid & 63, ln = lane & 15, kq = lane >> 4;
  const int mb = blockIdx.x >> 3, nb = blockIdx.x & 7;
  const int mrow = mb * 64 + w * 16 + ln;
  f4v acc[4] = {{0,0,0,0},{0,0,0,0},{0,0,0,0},{0,0,0,0}};
  for (int ks = 0; ks < 16; ++ks) {
    const float* ap = enc + (size_t)mrow * 512 + ks * 32 + kq * 8;
    s8v af;
#pragma unroll
    for (int j = 0; j < 8; ++j) af[j] = (short)f2bf(ap[j]);
#pragma unroll
    for (int nt = 0; nt < 4; ++nt) {
      int n = nb * 64 + nt * 16 + ln;
      const float* up = Ua + (size_t)n * 512 + ks * 32 + kq * 8;
      s8v bf;
#pragma unroll
      for (int j = 0; j < 8; ++j) bf[j] = (short)f2bf(up[j]);
      acc[nt] = mfma16(af, bf, acc[nt]);
    }
  }
#pragma unroll
  for (int nt = 0; nt < 4; ++nt) {
    int n = nb * 64 + nt * 16 + ln;
    float bias = bu[n];
#pragma unroll
    for (int r = 0; r < 4; ++r) {
      int gm = mb * 64 + w * 16 + kq * 4 + r;
      keysb[(size_t)gm * 512 + n] = f2bf(__expf(2.f * (acc[nt][r] + bias)));
    }
  }
}

// ---------------------------------------------------------------------------
// encpT[b][n][s] = fp8(enc[b,s]·Wih[n] + bih[n]),  n<1536  (TRANSPOSED)
// ---------------------------------------------------------------------------
__global__ void __launch_bounds__(256) encp_kernel(
    const float* __restrict__ enc, const float* __restrict__ Wih,
    const float* __restrict__ bih, unsigned char* __restrict__ encpt) {
  const int tid = threadIdx.x;
  const int w = tid >> 6, lane = tid & 63, ln = lane & 15, kq = lane >> 4;
  const int mb = blockIdx.x, nb = blockIdx.y;
  const int mrow = mb * 64 + w * 16 + ln;
  f4v acc[4] = {{0,0,0,0},{0,0,0,0},{0,0,0,0},{0,0,0,0}};
  for (int ks = 0; ks < 16; ++ks) {
    const float* ap = enc + (size_t)mrow * 512 + ks * 32 + kq * 8;
    s8v af;
#pragma unroll
    for (int j = 0; j < 8; ++j) af[j] = (short)f2bf(ap[j]);
#pragma unroll
    for (int nt = 0; nt < 4; ++nt) {
      int n = nb * 64 + nt * 16 + ln;
      const float* up = Wih + (size_t)n * 512 + ks * 32 + kq * 8;
      s8v bf;
#pragma unroll
      for (int j = 0; j < 8; ++j) bf[j] = (short)f2bf(up[j]);
      acc[nt] = mfma16(af, bf, acc[nt]);
    }
  }
#pragma unroll
  for (int nt = 0; nt < 4; ++nt) {
    int n = nb * 64 + nt * 16 + ln;
    float bias = bih[n];
#pragma unroll
    for (int r = 0; r < 4; ++r) {
      int gm = mb * 64 + w * 16 + kq * 4 + r;
      int b = gm >> 8, s = gm & 255;
      float v = acc[nt][r] + bias;
      int pk = __builtin_amdgcn_cvt_pk_fp8_f32(v, v, 0, false);
      encpt[((size_t)b * 1536 + n) * 256 + s] = (unsigned char)(pk & 0xff);
    }
  }
}

// ---------------------------------------------------------------------------
// persistent decoder: 256 blocks x 512 threads, 8 groups of 32 (group=bid&7)
// ---------------------------------------------------------------------------
__global__ void __launch_bounds__(512, 1) decoder_kernel(
    const float* __restrict__ ba_, const float* __restrict__ va_,
    const float* __restrict__ bhh_, const float* __restrict__ bout_,
    const unsigned short* __restrict__ wcat, const unsigned short* __restrict__ keysb,
    const unsigned char* __restrict__ encpt, unsigned* __restrict__ bar,
    unsigned short* __restrict__ hbf, float* __restrict__ qst,
    float* __restrict__ ghst, float* __restrict__ wbuf, float* __restrict__ out) {
  const int bid = blockIdx.x, tid = threadIdx.x;
  const int w = tid >> 6, lane = tid & 63, ln = lane & 15, kq = lane >> 4;
  const int g = bid & 7, p = bid >> 3;           // group (XCD), slot in group

  float* logits = out;
  float* hfin   = out + OUT_HFIN;
  float* attn   = out + OUT_ATTN;

  __shared__ unsigned short hA[16][520];         // P1 h stage (rows 8-15 zero)
  __shared__ float evqf[4096];                   // P2 Eq f32 [8][512]
  __shared__ float swl[8][256];                  // P3 staged w
  __shared__ float zL[8];
  __shared__ float giL[8][48];
  __shared__ float hL[8][16];                    // persistent h cols

  unsigned gen = 0;
  unsigned* gcnt  = bar + g * 32;
  unsigned* gflag = bar + g * 32 + 16;

  // ---- loop invariants ---------------------------------------------------
  float vav[8]; float vasum;
  {
    float vs = 0.f;
#pragma unroll
    for (int jj = 0; jj < 8; ++jj) { vav[jj] = va_[lane * 8 + jj]; vs += vav[jj]; }
#pragma unroll
    for (int off = 32; off > 0; off >>= 1) vs += __shfl_xor(vs, off, 64);
    vasum = vs;
  }
  // P1: wave w<5 owns col-tile ut = p*5+w (160 tiles = 2560 cols per group)
  const int ut = p * 5 + ((w < 5) ? w : 0);
  const int col = ut * 16 + ln;
  const int rg = (col < 512) ? 0 : (col < 2048) ? 1 : 2;
  const float pbias = (rg == 0) ? ba_[col]
                     : (rg == 1) ? bhh_[col - 512] : bout_[col - 2048];
  const s8v* wp = (const s8v*)(wcat + (size_t)col * 512);

  // init LDS
  if (tid < 64) {
    int b = tid >> 3, i2 = tid & 7;
    hL[b][i2 * 2] = 0.f; hL[b][i2 * 2 + 1] = 0.f;
  }
  for (int i2 = tid; i2 < 1040; i2 += 512) ((u64*)hA)[1040 + i2] = 0ull;
  __syncthreads();

#pragma clang loop unroll(disable)
  for (int it = 0; it <= 256; ++it) {
    // ============ P1: [q|gh|logits_{it-1}] = h @ Wcat^T ====================
    {
      // hbf: [64][512] bf16 -> 128 u64/batch, 1024 u64/group  (R9 bug: *512)
      const u64* hb = (const u64*)hbf + (size_t)g * 1024;
      u64 t0 = cload64(hb + tid), t1 = cload64(hb + 512 + tid);
      int r0 = tid >> 7, c0 = tid & 127;
      ((u64*)hA)[r0 * 130 + c0] = t0;
      int i1 = 512 + tid, r1 = i1 >> 7, c1 = i1 & 127;
      ((u64*)hA)[r1 * 130 + c1] = t1;
    }
    __syncthreads();
    if (w < 5 && !((rg == 2 && it == 0) || (rg != 2 && it == 256))) {
      f4v acc = {0.f, 0.f, 0.f, 0.f};
#pragma unroll
      for (int ks = 0; ks < 16; ++ks) {
        s8v af = *(const s8v*)&hA[ln][ks * 32 + kq * 8];
        acc = mfma16(af, wp[ks * 4 + kq], acc);
      }
      if (kq < 2) {                              // M rows 8-15 are padding
#pragma unroll
        for (int r = 0; r < 4; ++r) {
          int gb = g * 8 + kq * 4 + r;
          float v = acc[r] + pbias;
          if (rg == 0)
            cstore(qst + (size_t)gb * 512 + col, v);
          else if (rg == 1)
            cstore(ghst + (size_t)gb * 1536 + (col - 512), v);
          else
            cstore(logits + (size_t)(it - 1) * 32768 + (size_t)gb * 512 + (col - 2048), v);
        }
      }
    }
    gbar(gcnt, gflag, gen);
    if (it == 256) break;

    // ============ P2: scores for s-slice [8p,8p+8), 8 batches ==============
    {
      const float* qsrc = qst + (size_t)g * 4096;
      float tq[8];
#pragma unroll
      for (int k = 0; k < 8; ++k) tq[k] = cload(qsrc + k * 512 + tid);
#pragma unroll
      for (int k = 0; k < 8; ++k) evqf[k * 512 + tid] = __expf(2.f * tq[k]);
    }
    __syncthreads();
    {
      const int s = p * 8 + w;                   // wave = one s
      const unsigned short* kbase =
          keysb + ((size_t)(g * 8) * 256 + s) * 512 + lane * 8;
#pragma unroll
      for (int b = 0; b < 8; ++b) {
        s8v kv = *(const s8v*)(kbase + (size_t)b * 131072);
        f4v e0 = *(const f4v*)&evqf[b * 512 + lane * 8];
        f4v e1 = *(const f4v*)&evqf[b * 512 + lane * 8 + 4];
        float a2 = 0.f;
#pragma unroll
        for (int jj = 0; jj < 8; ++jj) {
          float eq = (jj < 4) ? e0[jj & 3] : e1[jj & 3];
          float P = eq * bf2f((unsigned short)kv[jj]);
          a2 += vav[jj] * __builtin_amdgcn_rcpf(1.f + P);
        }
#pragma unroll
        for (int off = 32; off > 0; off >>= 1) a2 += __shfl_xor(a2, off, 64);
        if (lane == 0)
          cstore(wbuf + (size_t)(g * 8 + b) * 256 + s, __expf(vasum - 2.f * a2));
      }
    }
    gbar(gcnt, gflag, gen);

    // ============ P3: gi cols [16p,16p+16) + GRU + attn ====================
    float ghv[6] = {0, 0, 0, 0, 0, 0};
    if (tid < 64) {                              // prefetch gh (2 cols x 3 gates)
      int b = tid >> 3, i2 = tid & 7;
      const float* gb_ = ghst + (size_t)(g * 8 + b) * 1536 + p * 16 + i2 * 2;
      ghv[0] = cload(gb_);        ghv[1] = cload(gb_ + 1);
      ghv[2] = cload(gb_ + 512);  ghv[3] = cload(gb_ + 513);
      ghv[4] = cload(gb_ + 1024); ghv[5] = cload(gb_ + 1025);
    }
    {
      const float* wsrc = wbuf + (size_t)g * 2048;
      float t0 = cload(wsrc + tid),        t1 = cload(wsrc + 512 + tid);
      float t2 = cload(wsrc + 1024 + tid), t3 = cload(wsrc + 1536 + tid);
      ((float*)swl)[tid] = t0;        ((float*)swl)[512 + tid] = t1;
      ((float*)swl)[1024 + tid] = t2; ((float*)swl)[1536 + tid] = t3;
    }
    __syncthreads();
    {
      // Z for batch w
      float z4 = swl[w][lane] + swl[w][64 + lane] + swl[w][128 + lane] +
                 swl[w][192 + lane];
#pragma unroll
      for (int off = 32; off > 0; off >>= 1) z4 += __shfl_xor(z4, off, 64);
      if (lane == 0) zL[w] = z4;
      // gi rows for batch w: 48 Wih-rows, lane <-> 4 s-values
      f4v wv = *(const f4v*)&swl[w][lane * 4];
      const unsigned char* ebase =
          encpt + (size_t)(g * 8 + w) * 393216u + (size_t)lane * 4;
#pragma unroll 8
      for (int cp = 0; cp < 48; ++cp) {
        int n = (cp >> 4) * 512 + p * 16 + (cp & 15);
        unsigned ev = *(const unsigned*)(ebase + (size_t)n * 256);
        f2v lo = __builtin_amdgcn_cvt_pk_f32_fp8((int)ev, false);
        f2v hi = __builtin_amdgcn_cvt_pk_f32_fp8((int)ev, true);
        float acc = wv[0] * lo[0] + wv[1] * lo[1] + wv[2] * hi[0] + wv[3] * hi[1];
#pragma unroll
        for (int off = 32; off > 0; off >>= 1) acc += __shfl_xor(acc, off, 64);
        if (lane == 0) giL[w][cp] = acc;
      }
    }
    __syncthreads();
    if (tid < 64) {
      const int b = tid >> 3, i2 = tid & 7;
      const int colg = p * 16 + i2 * 2;
      float iZ = __builtin_amdgcn_rcpf(zL[b]);
      int c = i2 * 2;
      float rr = sigm(giL[b][c] * iZ + ghv[0]);
      float zz = sigm(giL[b][16 + c] * iZ + ghv[2]);
      float nn = tanh2(giL[b][32 + c] * iZ + rr * ghv[4]);
      float hn0 = (1.f - zz) * nn + zz * hL[b][c];
      hL[b][c] = hn0;
      c++;
      rr = sigm(giL[b][c] * iZ + ghv[1]);
      zz = sigm(giL[b][16 + c] * iZ + ghv[3]);
      nn = tanh2(giL[b][32 + c] * iZ + rr * ghv[5]);
      float hn1 = (1.f - zz) * nn + zz * hL[b][c];
      hL[b][c] = hn1;
      unsigned pk = (unsigned)f2bf(hn0) | ((unsigned)f2bf(hn1) << 16);
      cstoreu((unsigned*)hbf + (size_t)(g * 8 + b) * 256 + p * 8 + i2, pk);
      if (it == 255) {
        hfin[(size_t)(g * 8 + b) * 512 + colg]     = hn0;
        hfin[(size_t)(g * 8 + b) * 512 + colg + 1] = hn1;
      }
      attn[(size_t)(g * 8 + b) * 65536 + (size_t)it * 256 + p * 8 + i2] =
          swl[b][p * 8 + i2] * iZ;
    }
    gbar(gcnt, gflag, gen);
  }

  // -------- finale: log_softmax on own group's rows (bias already added) ---
#pragma clang loop unroll(disable)
  for (int jb = 0; jb < 8; ++jb) {
    int row = (p * 8 + w) * 64 + g * 8 + jb;
    const u64* xr64 = (const u64*)(logits + (size_t)row * 512) + lane * 4;
    u64 t4[4];
#pragma unroll
    for (int jj = 0; jj < 4; ++jj) t4[jj] = cload64(xr64 + jj);
    union { u64 u[4]; float f[8]; } xu;
#pragma unroll
    for (int jj = 0; jj < 4; ++jj) xu.u[jj] = t4[jj];
    float mx = xu.f[0];
#pragma unroll
    for (int jj = 1; jj < 8; ++jj) mx = fmaxf(mx, xu.f[jj]);
#pragma unroll
    for (int off = 32; off > 0; off >>= 1) mx = fmaxf(mx, __shfl_xor(mx, off, 64));
    float sm = 0.f;
#pragma unroll
    for (int jj = 0; jj < 8; ++jj) sm += __expf(xu.f[jj] - mx);
#pragma unroll
    for (int off = 32; off > 0; off >>= 1) sm += __shfl_xor(sm, off, 64);
    float lse = mx + __logf(sm);
    float* xw = logits + (size_t)row * 512 + lane * 8;
    f4v o0, o1;
#pragma unroll
    for (int jj = 0; jj < 4; ++jj) { o0[jj] = xu.f[jj] - lse; o1[jj] = xu.f[4 + jj] - lse; }
    ((f4v*)xw)[0] = o0;
    ((f4v*)xw)[1] = o1;
  }
}

// ---------------------------------------------------------------------------
extern "C" void kernel_launch(void* const* d_in, const int* in_sizes, int n_in,
                              void* d_out, int out_size, void* d_ws, size_t ws_size,
                              hipStream_t stream) {
  const float* enc  = (const float*)d_in[0];
  const float* Wa   = (const float*)d_in[1];
  const float* ba   = (const float*)d_in[2];
  const float* Ua   = (const float*)d_in[3];
  const float* bu   = (const float*)d_in[4];
  const float* Va   = (const float*)d_in[5];
  // d_in[6] = bv : softmax-invariant, unused
  const float* Wih  = (const float*)d_in[7];
  const float* bih  = (const float*)d_in[8];
  const float* Whh  = (const float*)d_in[9];
  const float* bhh  = (const float*)d_in[10];
  const float* Wout = (const float*)d_in[11];
  const float* bout = (const float*)d_in[12];
  (void)in_sizes; (void)n_in; (void)out_size; (void)ws_size;

  char* ws = (char*)d_ws;
  unsigned*       bar   = (unsigned*)(ws + OFF_BAR);
  unsigned short* hbf   = (unsigned short*)(ws + OFF_HBF);
  float*          qst   = (float*)(ws + OFF_Q);
  float*          ghst  = (float*)(ws + OFF_GH);
  float*          wbuf  = (float*)(ws + OFF_WB);
  unsigned short* wcat  = (unsigned short*)(ws + OFF_WCAT);
  unsigned short* keysb = (unsigned short*)(ws + OFF_KEYS);
  unsigned char*  encpt = (unsigned char*)(ws + OFF_ENCPT);

  hipMemsetAsync(d_ws, 0, MEMSET_BYTES, stream);       // bar + hbf (h0 = 0)
  prep_kernel<<<512, 256, 0, stream>>>(Wa, Whh, Wout, wcat);
  keys_kernel<<<2048, 256, 0, stream>>>(enc, Ua, bu, keysb);
  encp_kernel<<<dim3(256, 24), 256, 0, stream>>>(enc, Wih, bih, encpt);
  decoder_kernel<<<256, 512, 0, stream>>>(ba, Va, bhh, bout,
                                          wcat, keysb, encpt, bar,
                                          hbf, qst, ghst, wbuf, (float*)d_out);
}

// Round 6
// 8682.426 us; speedup vs baseline: 2.2864x; 1.3532x over previous
//
#include <hip/hip_runtime.h>

// ============================================================================
// AttnDecoderRNN round 11 = R10 + two latency fixes (structure unchanged):
//  1. Store-slot barrier.  R10's gbar did 32 fetch-adds on ONE LLC line:
//     RMWs serialize at ~200ns each = ~6.4us/barrier, 3 barriers = ~19us of
//     the 43us step.  Now: each block STORES gen to its own slot (posted,
//     parallel); leader polls 32 slots (2 lines) and posts a release flag.
//  2. Batched fetch issue.  Chip sat at ~770 GB/s in both R8 (64 blk) and
//     R10 (256 blk) = outstanding-lines x latency limit, not BW.  P3 now
//     issues all 48 encpt loads into registers before consuming; P2 issues
//     all 8 key loads up front.
//  Numerics untouched (absmax 0.03125 expected unchanged).
// ============================================================================

typedef short s8v __attribute__((ext_vector_type(8)));
typedef float f4v __attribute__((ext_vector_type(4)));
typedef float f2v __attribute__((ext_vector_type(2)));
typedef unsigned long long u64;

// ws byte offsets
#define OFF_BAR    0u          // 8 groups x 64 uints: [0..31] slots, [48] flag
#define OFF_HBF    4096u       // [64][512] bf16 h broadcast
#define OFF_Q      69632u      // [64][512] f32 (q + ba)
#define OFF_GH     200704u     // [64][1536] f32 (gh + bhh)
#define OFF_WB     593920u     // [64][256] f32 unnormalized softmax weights
#define OFF_WCAT   659456u     // [2560][512] bf16 : Wa | Whh | Wout
#define OFF_KEYS   3280896u    // [64*256][512] bf16 : Ek = exp(2*(Ua.enc+bu))
#define OFF_ENCPT  20058112u   // [64][1536][256] fp8 : (Wih.enc + bih)^T
#define WS_FULL    45223936u
#define MEMSET_BYTES 69632u    // bar + hbf

// d_out offsets (floats)
#define OUT_HFIN   8388608u
#define OUT_ATTN   8421376u

__device__ __forceinline__ unsigned short f2bf(float f) {
  union { float f; unsigned u; } a; a.f = f;
  unsigned r = a.u + 0x7fffu + ((a.u >> 16) & 1u);
  return (unsigned short)(r >> 16);
}
__device__ __forceinline__ float bf2f(unsigned short h) {
  union { unsigned u; float f; } a; a.u = (unsigned)h << 16; return a.f;
}
__device__ __forceinline__ float cload(const float* p) {
  return __hip_atomic_load(p, __ATOMIC_RELAXED, __HIP_MEMORY_SCOPE_AGENT);
}
__device__ __forceinline__ void cstore(float* p, float v) {
  __hip_atomic_store(p, v, __ATOMIC_RELAXED, __HIP_MEMORY_SCOPE_AGENT);
}
__device__ __forceinline__ void cstoreu(unsigned* p, unsigned v) {
  __hip_atomic_store(p, v, __ATOMIC_RELAXED, __HIP_MEMORY_SCOPE_AGENT);
}
__device__ __forceinline__ u64 cload64(const u64* p) {
  return __hip_atomic_load(p, __ATOMIC_RELAXED, __HIP_MEMORY_SCOPE_AGENT);
}
__device__ __forceinline__ float sigm(float x) {
  return __builtin_amdgcn_rcpf(1.f + __expf(-x));
}
__device__ __forceinline__ float tanh2(float x) {
  return 1.f - 2.f * __builtin_amdgcn_rcpf(1.f + __expf(x + x));
}
__device__ __forceinline__ f4v mfma16(s8v a, s8v b, f4v c) {
  return __builtin_amdgcn_mfma_f32_16x16x32_bf16(a, b, c, 0, 0, 0);
}

// store-slot barrier: block p stores gen to slot p (posted, parallel);
// leader (p==0) polls the 32 slots then posts release flag at uint 48.
__device__ __forceinline__ void gbar(unsigned* gb, int p, unsigned& gen) {
  asm volatile("s_waitcnt vmcnt(0) lgkmcnt(0)" ::: "memory");
  __syncthreads();
  if (threadIdx.x == 0) {
    __atomic_signal_fence(__ATOMIC_SEQ_CST);
    gen++;
    __hip_atomic_store(gb + p, gen, __ATOMIC_RELAXED, __HIP_MEMORY_SCOPE_AGENT);
    if (p == 0) {
      for (;;) {
        unsigned mn = 0xffffffffu;
#pragma unroll
        for (int i = 0; i < 32; ++i) {
          unsigned v = __hip_atomic_load(gb + i, __ATOMIC_RELAXED,
                                         __HIP_MEMORY_SCOPE_AGENT);
          mn = (v < mn) ? v : mn;
        }
        if (mn >= gen) break;
        __builtin_amdgcn_s_sleep(0);
      }
      __hip_atomic_store(gb + 48, gen, __ATOMIC_RELAXED,
                         __HIP_MEMORY_SCOPE_AGENT);
    } else {
      while (__hip_atomic_load(gb + 48, __ATOMIC_RELAXED,
                               __HIP_MEMORY_SCOPE_AGENT) < gen)
        __builtin_amdgcn_s_sleep(1);
    }
    __atomic_signal_fence(__ATOMIC_SEQ_CST);
  }
  __syncthreads();
}

// ---------------------------------------------------------------------------
// prep: wcat = [Wa|Whh|Wout] bf16
// ---------------------------------------------------------------------------
__global__ void __launch_bounds__(256) prep_kernel(
    const float* __restrict__ Wa, const float* __restrict__ Whh,
    const float* __restrict__ Wout, unsigned short* __restrict__ wcat) {
  const size_t gid = (size_t)blockIdx.x * 256 + threadIdx.x;
  const size_t stride = (size_t)gridDim.x * 256;
  for (size_t i = gid; i < 1310720u; i += stride) {
    float v;
    if (i < 262144u)       v = Wa[i];
    else if (i < 1048576u) v = Whh[i - 262144u];
    else                   v = Wout[i - 1048576u];
    wcat[i] = f2bf(v);
  }
}

// ---------------------------------------------------------------------------
// keys[b*256+s][h] = exp(2*(enc[b,s]·Ua[h] + bu[h]))  (bf16)
// ---------------------------------------------------------------------------
__global__ void __launch_bounds__(256) keys_kernel(
    const float* __restrict__ enc, const float* __restrict__ Ua,
    const float* __restrict__ bu, unsigned short* __restrict__ keysb) {
  const int tid = threadIdx.x;
  const int w = tid >> 6, lane = tid & 63, ln = lane & 15, kq = lane >> 4;
  const int mb = blockIdx.x >> 3, nb = blockIdx.x & 7;
  const int mrow = mb * 64 + w * 16 + ln;
  f4v acc[4] = {{0,0,0,0},{0,0,0,0},{0,0,0,0},{0,0,0,0}};
  for (int ks = 0; ks < 16; ++ks) {
    const float* ap = enc + (size_t)mrow * 512 + ks * 32 + kq * 8;
    s8v af;
#pragma unroll
    for (int j = 0; j < 8; ++j) af[j] = (short)f2bf(ap[j]);
#pragma unroll
    for (int nt = 0; nt < 4; ++nt) {
      int n = nb * 64 + nt * 16 + ln;
      const float* up = Ua + (size_t)n * 512 + ks * 32 + kq * 8;
      s8v bf;
#pragma unroll
      for (int j = 0; j < 8; ++j) bf[j] = (short)f2bf(up[j]);
      acc[nt] = mfma16(af, bf, acc[nt]);
    }
  }
#pragma unroll
  for (int nt = 0; nt < 4; ++nt) {
    int n = nb * 64 + nt * 16 + ln;
    float bias = bu[n];
#pragma unroll
    for (int r = 0; r < 4; ++r) {
      int gm = mb * 64 + w * 16 + kq * 4 + r;
      keysb[(size_t)gm * 512 + n] = f2bf(__expf(2.f * (acc[nt][r] + bias)));
    }
  }
}

// ---------------------------------------------------------------------------
// encpT[b][n][s] = fp8(enc[b,s]·Wih[n] + bih[n]),  n<1536  (TRANSPOSED)
// ---------------------------------------------------------------------------
__global__ void __launch_bounds__(256) encp_kernel(
    const float* __restrict__ enc, const float* __restrict__ Wih,
    const float* __restrict__ bih, unsigned char* __restrict__ encpt) {
  const int tid = threadIdx.x;
  const int w = tid >> 6, lane = tid & 63, ln = lane & 15, kq = lane >> 4;
  const int mb = blockIdx.x, nb = blockIdx.y;
  const int mrow = mb * 64 + w * 16 + ln;
  f4v acc[4] = {{0,0,0,0},{0,0,0,0},{0,0,0,0},{0,0,0,0}};
  for (int ks = 0; ks < 16; ++ks) {
    const float* ap = enc + (size_t)mrow * 512 + ks * 32 + kq * 8;
    s8v af;
#pragma unroll
    for (int j = 0; j < 8; ++j) af[j] = (short)f2bf(ap[j]);
#pragma unroll
    for (int nt = 0; nt < 4; ++nt) {
      int n = nb * 64 + nt * 16 + ln;
      const float* up = Wih + (size_t)n * 512 + ks * 32 + kq * 8;
      s8v bf;
#pragma unroll
      for (int j = 0; j < 8; ++j) bf[j] = (short)f2bf(up[j]);
      acc[nt] = mfma16(af, bf, acc[nt]);
    }
  }
#pragma unroll
  for (int nt = 0; nt < 4; ++nt) {
    int n = nb * 64 + nt * 16 + ln;
    float bias = bih[n];
#pragma unroll
    for (int r = 0; r < 4; ++r) {
      int gm = mb * 64 + w * 16 + kq * 4 + r;
      int b = gm >> 8, s = gm & 255;
      float v = acc[nt][r] + bias;
      int pk = __builtin_amdgcn_cvt_pk_fp8_f32(v, v, 0, false);
      encpt[((size_t)b * 1536 + n) * 256 + s] = (unsigned char)(pk & 0xff);
    }
  }
}

// ---------------------------------------------------------------------------
// persistent decoder: 256 blocks x 512 threads, 8 groups of 32 (group=bid&7)
// ---------------------------------------------------------------------------
__global__ void __launch_bounds__(512, 1) decoder_kernel(
    const float* __restrict__ ba_, const float* __restrict__ va_,
    const float* __restrict__ bhh_, const float* __restrict__ bout_,
    const unsigned short* __restrict__ wcat, const unsigned short* __restrict__ keysb,
    const unsigned char* __restrict__ encpt, unsigned* __restrict__ bar,
    unsigned short* __restrict__ hbf, float* __restrict__ qst,
    float* __restrict__ ghst, float* __restrict__ wbuf, float* __restrict__ out) {
  const int bid = blockIdx.x, tid = threadIdx.x;
  const int w = tid >> 6, lane = tid & 63, ln = lane & 15, kq = lane >> 4;
  const int g = bid & 7, p = bid >> 3;           // group (XCD), slot in group

  float* logits = out;
  float* hfin   = out + OUT_HFIN;
  float* attn   = out + OUT_ATTN;

  __shared__ unsigned short hA[16][520];         // P1 h stage (rows 8-15 zero)
  __shared__ float evqf[4096];                   // P2 Eq f32 [8][512]
  __shared__ float swl[8][256];                  // P3 staged w
  __shared__ float zL[8];
  __shared__ float giL[8][48];
  __shared__ float hL[8][16];                    // persistent h cols

  unsigned gen = 0;
  unsigned* gb = bar + g * 64;

  // ---- loop invariants ---------------------------------------------------
  float vav[8]; float vasum;
  {
    float vs = 0.f;
#pragma unroll
    for (int jj = 0; jj < 8; ++jj) { vav[jj] = va_[lane * 8 + jj]; vs += vav[jj]; }
#pragma unroll
    for (int off = 32; off > 0; off >>= 1) vs += __shfl_xor(vs, off, 64);
    vasum = vs;
  }
  // P1: wave w<5 owns col-tile ut = p*5+w (160 tiles = 2560 cols per group)
  const int ut = p * 5 + ((w < 5) ? w : 0);
  const int col = ut * 16 + ln;
  const int rg = (col < 512) ? 0 : (col < 2048) ? 1 : 2;
  const float pbias = (rg == 0) ? ba_[col]
                     : (rg == 1) ? bhh_[col - 512] : bout_[col - 2048];
  const s8v* wp = (const s8v*)(wcat + (size_t)col * 512);

  // init LDS
  if (tid < 64) {
    int b = tid >> 3, i2 = tid & 7;
    hL[b][i2 * 2] = 0.f; hL[b][i2 * 2 + 1] = 0.f;
  }
  for (int i2 = tid; i2 < 1040; i2 += 512) ((u64*)hA)[1040 + i2] = 0ull;
  __syncthreads();

#pragma clang loop unroll(disable)
  for (int it = 0; it <= 256; ++it) {
    // ============ P1: [q|gh|logits_{it-1}] = h @ Wcat^T ====================
    {
      const u64* hb = (const u64*)hbf + (size_t)g * 1024;
      u64 t0 = cload64(hb + tid), t1 = cload64(hb + 512 + tid);
      int r0 = tid >> 7, c0 = tid & 127;
      ((u64*)hA)[r0 * 130 + c0] = t0;
      int i1 = 512 + tid, r1 = i1 >> 7, c1 = i1 & 127;
      ((u64*)hA)[r1 * 130 + c1] = t1;
    }
    __syncthreads();
    if (w < 5 && !((rg == 2 && it == 0) || (rg != 2 && it == 256))) {
      f4v acc = {0.f, 0.f, 0.f, 0.f};
#pragma unroll
      for (int ks = 0; ks < 16; ++ks) {
        s8v af = *(const s8v*)&hA[ln][ks * 32 + kq * 8];
        acc = mfma16(af, wp[ks * 4 + kq], acc);
      }
      if (kq < 2) {                              // M rows 8-15 are padding
#pragma unroll
        for (int r = 0; r < 4; ++r) {
          int gbb = g * 8 + kq * 4 + r;
          float v = acc[r] + pbias;
          if (rg == 0)
            cstore(qst + (size_t)gbb * 512 + col, v);
          else if (rg == 1)
            cstore(ghst + (size_t)gbb * 1536 + (col - 512), v);
          else
            cstore(logits + (size_t)(it - 1) * 32768 + (size_t)gbb * 512 + (col - 2048), v);
        }
      }
    }
    gbar(gb, p, gen);
    if (it == 256) break;

    // ============ P2: scores for s-slice [8p,8p+8), 8 batches ==============
    {
      const float* qsrc = qst + (size_t)g * 4096;
      float tq[8];
#pragma unroll
      for (int k = 0; k < 8; ++k) tq[k] = cload(qsrc + k * 512 + tid);
#pragma unroll
      for (int k = 0; k < 8; ++k) evqf[k * 512 + tid] = __expf(2.f * tq[k]);
    }
    __syncthreads();
    {
      const int s = p * 8 + w;                   // wave = one s
      const unsigned short* kbase =
          keysb + ((size_t)(g * 8) * 256 + s) * 512 + lane * 8;
      // batch-issue all 8 key loads first (outstanding-lines throughput)
      s8v kv[8];
#pragma unroll
      for (int b = 0; b < 8; ++b)
        kv[b] = *(const s8v*)(kbase + (size_t)b * 131072);
#pragma unroll
      for (int b = 0; b < 8; ++b) {
        f4v e0 = *(const f4v*)&evqf[b * 512 + lane * 8];
        f4v e1 = *(const f4v*)&evqf[b * 512 + lane * 8 + 4];
        float a2 = 0.f;
#pragma unroll
        for (int jj = 0; jj < 8; ++jj) {
          float eq = (jj < 4) ? e0[jj & 3] : e1[jj & 3];
          float P = eq * bf2f((unsigned short)kv[b][jj]);
          a2 += vav[jj] * __builtin_amdgcn_rcpf(1.f + P);
        }
#pragma unroll
        for (int off = 32; off > 0; off >>= 1) a2 += __shfl_xor(a2, off, 64);
        if (lane == 0)
          cstore(wbuf + (size_t)(g * 8 + b) * 256 + s, __expf(vasum - 2.f * a2));
      }
    }
    gbar(gb, p, gen);

    // ============ P3: gi cols [16p,16p+16) + GRU + attn ====================
    float ghv[6] = {0, 0, 0, 0, 0, 0};
    if (tid < 64) {                              // prefetch gh (2 cols x 3 gates)
      int b = tid >> 3, i2 = tid & 7;
      const float* gb_ = ghst + (size_t)(g * 8 + b) * 1536 + p * 16 + i2 * 2;
      ghv[0] = cload(gb_);        ghv[1] = cload(gb_ + 1);
      ghv[2] = cload(gb_ + 512);  ghv[3] = cload(gb_ + 513);
      ghv[4] = cload(gb_ + 1024); ghv[5] = cload(gb_ + 1025);
    }
    {
      const float* wsrc = wbuf + (size_t)g * 2048;
      float t0 = cload(wsrc + tid),        t1 = cload(wsrc + 512 + tid);
      float t2 = cload(wsrc + 1024 + tid), t3 = cload(wsrc + 1536 + tid);
      ((float*)swl)[tid] = t0;        ((float*)swl)[512 + tid] = t1;
      ((float*)swl)[1024 + tid] = t2; ((float*)swl)[1536 + tid] = t3;
    }
    __syncthreads();
    {
      // Z for batch w
      float z4 = swl[w][lane] + swl[w][64 + lane] + swl[w][128 + lane] +
                 swl[w][192 + lane];
#pragma unroll
      for (int off = 32; off > 0; off >>= 1) z4 += __shfl_xor(z4, off, 64);
      if (lane == 0) zL[w] = z4;
      // gi rows for batch w: 48 Wih-rows, lane <-> 4 s-values.
      // Issue ALL 48 loads into registers first, consume after.
      f4v wv = *(const f4v*)&swl[w][lane * 4];
      const unsigned char* ebase =
          encpt + (size_t)(g * 8 + w) * 393216u + (size_t)lane * 4;
      unsigned tv[48];
#pragma unroll
      for (int cp = 0; cp < 48; ++cp) {
        int n = (cp >> 4) * 512 + p * 16 + (cp & 15);
        tv[cp] = *(const unsigned*)(ebase + (size_t)n * 256);
      }
#pragma unroll
      for (int cp = 0; cp < 48; ++cp) {
        f2v lo = __builtin_amdgcn_cvt_pk_f32_fp8((int)tv[cp], false);
        f2v hi = __builtin_amdgcn_cvt_pk_f32_fp8((int)tv[cp], true);
        float acc = wv[0] * lo[0] + wv[1] * lo[1] + wv[2] * hi[0] + wv[3] * hi[1];
#pragma unroll
        for (int off = 32; off > 0; off >>= 1) acc += __shfl_xor(acc, off, 64);
        if (lane == 0) giL[w][cp] = acc;
      }
    }
    __syncthreads();
    if (tid < 64) {
      const int b = tid >> 3, i2 = tid & 7;
      const int colg = p * 16 + i2 * 2;
      float iZ = __builtin_amdgcn_rcpf(zL[b]);
      int c = i2 * 2;
      float rr = sigm(giL[b][c] * iZ + ghv[0]);
      float zz = sigm(giL[b][16 + c] * iZ + ghv[2]);
      float nn = tanh2(giL[b][32 + c] * iZ + rr * ghv[4]);
      float hn0 = (1.f - zz) * nn + zz * hL[b][c];
      hL[b][c] = hn0;
      c++;
      rr = sigm(giL[b][c] * iZ + ghv[1]);
      zz = sigm(giL[b][16 + c] * iZ + ghv[3]);
      nn = tanh2(giL[b][32 + c] * iZ + rr * ghv[5]);
      float hn1 = (1.f - zz) * nn + zz * hL[b][c];
      hL[b][c] = hn1;
      unsigned pk = (unsigned)f2bf(hn0) | ((unsigned)f2bf(hn1) << 16);
      cstoreu((unsigned*)hbf + (size_t)(g * 8 + b) * 256 + p * 8 + i2, pk);
      if (it == 255) {
        hfin[(size_t)(g * 8 + b) * 512 + colg]     = hn0;
        hfin[(size_t)(g * 8 + b) * 512 + colg + 1] = hn1;
      }
      attn[(size_t)(g * 8 + b) * 65536 + (size_t)it * 256 + p * 8 + i2] =
          swl[b][p * 8 + i2] * iZ;
    }
    gbar(gb, p, gen);
  }

  // -------- finale: log_softmax on own group's rows (bias already added) ---
#pragma clang loop unroll(disable)
  for (int jb = 0; jb < 8; ++jb) {
    int row = (p * 8 + w) * 64 + g * 8 + jb;
    const u64* xr64 = (const u64*)(logits + (size_t)row * 512) + lane * 4;
    u64 t4[4];
#pragma unroll
    for (int jj = 0; jj < 4; ++jj) t4[jj] = cload64(xr64 + jj);
    union { u64 u[4]; float f[8]; } xu;
#pragma unroll
    for (int jj = 0; jj < 4; ++jj) xu.u[jj] = t4[jj];
    float mx = xu.f[0];
#pragma unroll
    for (int jj = 1; jj < 8; ++jj) mx = fmaxf(mx, xu.f[jj]);
#pragma unroll
    for (int off = 32; off > 0; off >>= 1) mx = fmaxf(mx, __shfl_xor(mx, off, 64));
    float sm = 0.f;
#pragma unroll
    for (int jj = 0; jj < 8; ++jj) sm += __expf(xu.f[jj] - mx);
#pragma unroll
    for (int off = 32; off > 0; off >>= 1) sm += __shfl_xor(sm, off, 64);
    float lse = mx + __logf(sm);
    float* xw = logits + (size_t)row * 512 + lane * 8;
    f4v o0, o1;
#pragma unroll
    for (int jj = 0; jj < 4; ++jj) { o0[jj] = xu.f[jj] - lse; o1[jj] = xu.f[4 + jj] - lse; }
    ((f4v*)xw)[0] = o0;
    ((f4v*)xw)[1] = o1;
  }
}

// ---------------------------------------------------------------------------
extern "C" void kernel_launch(void* const* d_in, const int* in_sizes, int n_in,
                              void* d_out, int out_size, void* d_ws, size_t ws_size,
                              hipStream_t stream) {
  const float* enc  = (const float*)d_in[0];
  const float* Wa   = (const float*)d_in[1];
  const float* ba   = (const float*)d_in[2];
  const float* Ua   = (const float*)d_in[3];
  const float* bu   = (const float*)d_in[4];
  const float* Va   = (const float*)d_in[5];
  // d_in[6] = bv : softmax-invariant, unused
  const float* Wih  = (const float*)d_in[7];
  const float* bih  = (const float*)d_in[8];
  const float* Whh  = (const float*)d_in[9];
  const float* bhh  = (const float*)d_in[10];
  const float* Wout = (const float*)d_in[11];
  const float* bout = (const float*)d_in[12];
  (void)in_sizes; (void)n_in; (void)out_size; (void)ws_size;

  char* ws = (char*)d_ws;
  unsigned*       bar   = (unsigned*)(ws + OFF_BAR);
  unsigned short* hbf   = (unsigned short*)(ws + OFF_HBF);
  float*          qst   = (float*)(ws + OFF_Q);
  float*          ghst  = (float*)(ws + OFF_GH);
  float*          wbuf  = (float*)(ws + OFF_WB);
  unsigned short* wcat  = (unsigned short*)(ws + OFF_WCAT);
  unsigned short* keysb = (unsigned short*)(ws + OFF_KEYS);
  unsigned char*  encpt = (unsigned char*)(ws + OFF_ENCPT);

  hipMemsetAsync(d_ws, 0, MEMSET_BYTES, stream);       // bar + hbf (h0 = 0)
  prep_kernel<<<512, 256, 0, stream>>>(Wa, Whh, Wout, wcat);
  keys_kernel<<<2048, 256, 0, stream>>>(enc, Ua, bu, keysb);
  encp_kernel<<<dim3(256, 24), 256, 0, stream>>>(enc, Wih, bih, encpt);
  decoder_kernel<<<256, 512, 0, stream>>>(ba, Va, bhh, bout,
                                          wcat, keysb, encpt, bar,
                                          hbf, qst, ghst, wbuf, (float*)d_out);
}